// Round 1
// baseline (65.713 us; speedup 1.0000x reference)
//
#include <hip/hip_runtime.h>

// OneHotEncoder: per-row histogram of tokens, skipping pad_idx=0.
// tokens: [B=256, T=2048] int32 ; out: [B, VOCAB=32000] float32.
// Memory-bound on the 32.8 MB output write. One block per row; histogram
// lives in LDS as packed 2x16-bit counts (64000 B -> 2 blocks/CU), output
// streamed once with coalesced float4 stores.

#define VOCAB 32000
#define BLOCK 1024

__global__ __launch_bounds__(BLOCK)
void OneHotEncoder_43052752175267_kernel(const int* __restrict__ tokens,
                                         float* __restrict__ out,
                                         int T) {
    // Packed histogram: hist[i] holds counts for tokens 2i (low 16b) and 2i+1 (high 16b).
    // Max count = T = 2048 < 65536, so no carry into the neighboring half.
    __shared__ __align__(16) unsigned int hist[VOCAB / 2];  // 16000 u32 = 64000 B

    const int row = blockIdx.x;
    const int tid = threadIdx.x;

    // --- Phase 1: zero the LDS histogram (uint4-vectorized) ---
    uint4* h4 = (uint4*)hist;
    const uint4 z = make_uint4(0u, 0u, 0u, 0u);
    for (int i = tid; i < VOCAB / 8; i += BLOCK)  // 4000 uint4
        h4[i] = z;
    __syncthreads();

    // --- Phase 2: scan this row's tokens, DS-atomic into packed histogram ---
    const int* trow = tokens + (long long)row * T;
    for (int i = tid; i < T; i += BLOCK) {
        int tok = trow[i];
        if (tok != 0)
            atomicAdd(&hist[tok >> 1], 1u << ((tok & 1) << 4));
    }
    __syncthreads();

    // --- Phase 3: unpack and stream out, coalesced float4 stores ---
    float4* o4 = (float4*)(out + (long long)row * VOCAB);
    const uint2* h2 = (const uint2*)hist;
    for (int i = tid; i < VOCAB / 4; i += BLOCK) {  // 8000 float4
        uint2 h = h2[i];
        float4 f;
        f.x = (float)(h.x & 0xFFFFu);
        f.y = (float)(h.x >> 16);
        f.z = (float)(h.y & 0xFFFFu);
        f.w = (float)(h.y >> 16);
        o4[i] = f;
    }
}

extern "C" void kernel_launch(void* const* d_in, const int* in_sizes, int n_in,
                              void* d_out, int out_size, void* d_ws, size_t ws_size,
                              hipStream_t stream) {
    const int* tokens = (const int*)d_in[0];
    // d_in[1] (lengths) is unused by the reference computation.
    const int B = in_sizes[1];           // 256 (lengths has one entry per row)
    const int T = in_sizes[0] / B;       // 2048
    float* out = (float*)d_out;

    OneHotEncoder_43052752175267_kernel<<<dim3(B), dim3(BLOCK), 0, stream>>>(tokens, out, T);
}